// Round 5
// baseline (242.192 us; speedup 1.0000x reference)
//
#include <hip/hip_runtime.h>
#include <hip/hip_bf16.h>
#include <hip/hip_cooperative_groups.h>

namespace cg = cooperative_groups;

#define N_NODES 500000
#define N_FEAT 125
#define HID 128
#define OUTD 64
#define N_GRAPHS 4096
#define N_TYPES 100
#define WTILE 32
#define NTILES32 (N_NODES / WTILE)        /* 15625 exact — no tail handling */
#define NBLOCKS 256
#define NTHREADS 512
#define NWAVES 8
#define GRID_THREADS (NBLOCKS * NTHREADS)          // 131072
#define WPAD 136    /* bf16 row stride: 16B-aligned; 68 dwords == 4 mod 32 banks */
#define OPADF 68    /* f32 row stride, aliases bf16 scratch exactly */

typedef float f32x4 __attribute__((ext_vector_type(4)));
typedef short s16x8 __attribute__((ext_vector_type(8)));

// LDS layout (bytes)
#define OFF_T 0
#define SZ_T (N_TYPES * WPAD * 2)                  // 27200
#define OFF_W2 (OFF_T + SZ_T)
#define OFF_W3 (OFF_W2 + HID * WPAD * 2)           // +34816
#define OFF_B2 (OFF_W3 + OUTD * WPAD * 2)          // +17408
#define OFF_SCR (OFF_B2 + HID * 4)                 // -> 79936
#define SCR_BYTES (WTILE * WPAD * 2)               // 8704/wave
#define OFF_IDS (OFF_SCR + NWAVES * SCR_BYTES)     // 149568
#define LDS_BYTES (OFF_IDS + NWAVES * WTILE * 4)   // 150592 (<= 163840)

// ws layout (bytes)
#define WS_GSUM 0
#define WS_GCNT ((size_t)N_GRAPHS * OUTD * 4)      // 1048576
#define WS_TPK  (WS_GCNT + (size_t)N_GRAPHS * 4)   // 1064960
#define ZERO_DWORDS ((N_GRAPHS * OUTD + N_GRAPHS)) // gsum+gcnt dwords = 266240
#define N_TPK (N_TYPES * (HID / 2))                // 6400 packed bf16 pairs

__device__ __forceinline__ unsigned short f2bf(float f) {
  union { float f; unsigned u; } v; v.f = f;
  unsigned r = v.u + 0x7FFFu + ((v.u >> 16) & 1u);  // RNE
  return (unsigned short)(r >> 16);
}
__device__ __forceinline__ float bf2f(unsigned short u) {
  union { unsigned u; float f; } v; v.u = ((unsigned)u) << 16;
  return v.f;
}
__device__ __forceinline__ unsigned pk2bf(float a, float b) {
  __hip_bfloat162 h = __float22bfloat162_rn(float2{a, b});   // .x low16, .y high16
  union { __hip_bfloat162 h; unsigned u; } v; v.h = h;
  return v.u;
}

// Wave-local LDS ordering fence (DS pipe is in-order per wave). Proven R3/R4.
__device__ __forceinline__ void wavefence() {
  __builtin_amdgcn_sched_barrier(0);
  __builtin_amdgcn_wave_barrier();
  __builtin_amdgcn_sched_barrier(0);
}

extern "C" __global__ void __launch_bounds__(NTHREADS, 2)
gnn_fused(const float* __restrict__ pos, const int* __restrict__ z,
          const int* __restrict__ batch, const float* __restrict__ emb,
          const float* __restrict__ W1, const float* __restrict__ b1,
          const float* __restrict__ W2, const float* __restrict__ b2,
          const float* __restrict__ W3, const float* __restrict__ b3,
          float* __restrict__ gsum, int* __restrict__ gcnt,
          unsigned* __restrict__ Tpk, float* __restrict__ out)
{
  extern __shared__ char lds[];
  unsigned short* Tl  = (unsigned short*)(lds + OFF_T);
  unsigned short* w2t = (unsigned short*)(lds + OFF_W2);
  unsigned short* w3t = (unsigned short*)(lds + OFF_W3);
  float* bias2 = (float*)(lds + OFF_B2);

  const int t = threadIdx.x;
  const int gid = blockIdx.x * NTHREADS + t;

  // ================= phase A: zero accumulators + compute T (once, grid-wide)
  {
    unsigned* wz = (unsigned*)gsum;   // gsum||gcnt contiguous in ws
    for (int i = gid; i < ZERO_DWORDS; i += GRID_THREADS)
      __hip_atomic_store(&wz[i], 0u, __ATOMIC_RELAXED, __HIP_MEMORY_SCOPE_AGENT);

    if (gid < N_TPK) {                 // one wave per type g: lanes j0=2*lane
      const int g = gid >> 6, jp = gid & 63, j0 = 2 * jp;
      const float* er = emb + g * N_FEAT;      // wave-uniform -> s_loads
      float2 b = *(const float2*)&b1[j0];
      float a0 = b.x, a1 = b.y;
      for (int k = 0; k < N_FEAT; ++k) {
        float e = er[k];
        float2 w = *(const float2*)&W1[(3 + k) * HID + j0];
        a0 = fmaf(e, w.x, a0); a1 = fmaf(e, w.y, a1);
      }
      __hip_atomic_store(&Tpk[gid], pk2bf(a0, a1),
                         __ATOMIC_RELAXED, __HIP_MEMORY_SCOPE_AGENT);
    }
  }

  // ---- stage block-local weights (no cross-block dependency) ----
  for (int i = t; i < HID * HID; i += NTHREADS) {      // W2^T [n][k] bf16
    int k = i >> 7, n = i & 127;
    w2t[n * WPAD + k] = f2bf(W2[i]);
  }
  for (int i = t; i < HID * OUTD; i += NTHREADS) {     // W3^T [n][k] bf16
    int k = i >> 6, n = i & 63;
    w3t[n * WPAD + k] = f2bf(W3[i]);
  }
  if (t < HID) bias2[t] = b2[t];

  cg::this_grid().sync();   // T + zeros visible device-wide

  // ---- stage T from ws (agent-scope loads: cross-XCD coherent) ----
  for (int i = t; i < N_TPK; i += NTHREADS) {
    unsigned u = __hip_atomic_load(&Tpk[i], __ATOMIC_RELAXED, __HIP_MEMORY_SCOPE_AGENT);
    int g = i >> 6, jp = i & 63;
    *(unsigned*)(Tl + g * WPAD + 2 * jp) = u;
  }

  const int wave = t >> 6, lane = t & 63, quad = lane >> 4, l15 = lane & 15;
  unsigned short* xs = (unsigned short*)(lds + OFF_SCR + wave * SCR_BYTES);
  float* xo = (float*)xs;                          // aliases xs (wave-order-safe)
  int* ids = (int*)(lds + OFF_IDS) + wave * WTILE;

  // ---- per-lane W1 pos-row coefficients, fp32, tile-invariant (96 VGPRs) ----
  float w1r[3][4][8];
  #pragma unroll
  for (int c = 0; c < 3; ++c)
    #pragma unroll
    for (int k = 0; k < 4; ++k)
      #pragma unroll
      for (int j = 0; j < 8; ++j)
        w1r[c][k][j] = W1[c * HID + k * 32 + quad * 8 + j];

  __syncthreads();   // Tl staged by all waves of this block

  // ================= phase B: main loop (R4 body, proven) =================
  const int gwave = blockIdx.x * NWAVES + wave;

  for (int tile = gwave; tile < NTILES32; tile += NBLOCKS * NWAVES) {
    const int base = tile * WTILE;

    if (lane < WTILE) ids[lane] = batch[base + lane];

    // layer 1 in VALU, directly into MFMA B-fragments (x^T operand)
    s16x8 a[2][4];
    #pragma unroll
    for (int m = 0; m < 2; ++m) {
      const int node = base + m * 16 + l15;
      const int zi = z[node];
      const float px = pos[node * 3], py = pos[node * 3 + 1], pz = pos[node * 3 + 2];
      const unsigned short* Tr = Tl + zi * WPAD;
      #pragma unroll
      for (int k = 0; k < 4; ++k) {
        s16x8 tf = *(const s16x8*)(Tr + k * 32 + quad * 8);
        s16x8 fr;
        #pragma unroll
        for (int j = 0; j < 8; j += 2) {
          float v0 = bf2f((unsigned short)tf[j])
                   + px * w1r[0][k][j] + py * w1r[1][k][j] + pz * w1r[2][k][j];
          float v1 = bf2f((unsigned short)tf[j + 1])
                   + px * w1r[0][k][j + 1] + py * w1r[1][k][j + 1] + pz * w1r[2][k][j + 1];
          ((unsigned*)&fr)[j >> 1] = pk2bf(fmaxf(v0, 0.f), fmaxf(v1, 0.f));
        }
        a[m][k] = fr;
      }
    }

    // layer 2: D = W2^T(A) x h1^T(B) -> C: row=out-feature, col=node
    f32x4 acc[8][2] = {};
    #pragma unroll
    for (int oi = 0; oi < 8; ++oi)
      #pragma unroll
      for (int k = 0; k < 4; ++k) {
        s16x8 w = *(const s16x8*)(w2t + (oi * 16 + l15) * WPAD + k * 32 + quad * 8);
        acc[oi][0] = __builtin_amdgcn_mfma_f32_16x16x32_bf16(w, a[0][k], acc[oi][0], 0, 0, 0);
        acc[oi][1] = __builtin_amdgcn_mfma_f32_16x16x32_bf16(w, a[1][k], acc[oi][1], 0, 0, 0);
      }
    // epilogue 2: 4 consecutive features per lane -> packed b64 writes
    #pragma unroll
    for (int oi = 0; oi < 8; ++oi) {
      const int f0 = oi * 16 + quad * 4;
      f32x4 bv = *(const f32x4*)(bias2 + f0);
      #pragma unroll
      for (int m = 0; m < 2; ++m) {
        unsigned lo = pk2bf(fmaxf(acc[oi][m][0] + bv[0], 0.f),
                            fmaxf(acc[oi][m][1] + bv[1], 0.f));
        unsigned hi = pk2bf(fmaxf(acc[oi][m][2] + bv[2], 0.f),
                            fmaxf(acc[oi][m][3] + bv[3], 0.f));
        *(uint2*)(xs + (m * 16 + l15) * WPAD + f0) = uint2{lo, hi};
      }
    }
    wavefence();
    #pragma unroll
    for (int m = 0; m < 2; ++m)
      #pragma unroll
      for (int k = 0; k < 4; ++k)
        a[m][k] = *(const s16x8*)(xs + (m * 16 + l15) * WPAD + k * 32 + quad * 8);
    wavefence();

    // layer 3: D = W3^T x h2^T (b3 folded into finalize)
    f32x4 acc3[4][2] = {};
    #pragma unroll
    for (int oi = 0; oi < 4; ++oi)
      #pragma unroll
      for (int k = 0; k < 4; ++k) {
        s16x8 w = *(const s16x8*)(w3t + (oi * 16 + l15) * WPAD + k * 32 + quad * 8);
        acc3[oi][0] = __builtin_amdgcn_mfma_f32_16x16x32_bf16(w, a[0][k], acc3[oi][0], 0, 0, 0);
        acc3[oi][1] = __builtin_amdgcn_mfma_f32_16x16x32_bf16(w, a[1][k], acc3[oi][1], 0, 0, 0);
      }
    #pragma unroll
    for (int oi = 0; oi < 4; ++oi)
      #pragma unroll
      for (int m = 0; m < 2; ++m)
        *(f32x4*)(xo + (m * 16 + l15) * OPADF + oi * 16 + quad * 4) = acc3[oi][m];
    wavefence();

    // pool: sorted batch -> run-scan; ids wave-uniform -> uniform branches
    {
      const int o = lane;
      int cur = ids[0];
      float run = 0.f; int rc = 0;
      #pragma unroll 1
      for (int n = 0; n < WTILE; ++n) {
        int bb = ids[n];
        if (bb != cur) {
          atomicAdd(&gsum[cur * OUTD + o], run);
          if (o == 0) atomicAdd(&gcnt[cur], rc);
          run = 0.f; rc = 0; cur = bb;
        }
        run += xo[n * OPADF + o]; rc++;
      }
      atomicAdd(&gsum[cur * OUTD + o], run);
      if (o == 0) atomicAdd(&gcnt[cur], rc);
    }
    wavefence();   // next tile reuses xs/ids (same wave)
  }

  // ================= phase C: finalize (was a separate kernel) =============
  __threadfence();
  cg::this_grid().sync();

  #pragma unroll
  for (int rep = 0; rep < (N_GRAPHS * OUTD) / GRID_THREADS; ++rep) {
    int i = gid + rep * GRID_THREADS;
    int g = i >> 6, o = i & 63;
    int c = __hip_atomic_load(&gcnt[g], __ATOMIC_RELAXED, __HIP_MEMORY_SCOPE_AGENT);
    float s = __hip_atomic_load(&gsum[i], __ATOMIC_RELAXED, __HIP_MEMORY_SCOPE_AGENT);
    out[i] = (c > 0) ? (s / (float)c + b3[o]) : 0.f;
  }
}

extern "C" void kernel_launch(void* const* d_in, const int* in_sizes, int n_in,
                              void* d_out, int out_size, void* d_ws, size_t ws_size,
                              hipStream_t stream) {
  const float* pos  = (const float*)d_in[0];
  const int*   z    = (const int*)d_in[1];
  const int*   batch= (const int*)d_in[2];
  const float* emb  = (const float*)d_in[3];
  const float* W1   = (const float*)d_in[4];
  const float* b1   = (const float*)d_in[5];
  const float* W2   = (const float*)d_in[6];
  const float* b2   = (const float*)d_in[7];
  const float* W3   = (const float*)d_in[8];
  const float* b3   = (const float*)d_in[9];

  float*    gsum = (float*)d_ws;
  int*      gcnt = (int*)((char*)d_ws + WS_GCNT);
  unsigned* Tpk  = (unsigned*)((char*)d_ws + WS_TPK);
  float*    outp = (float*)d_out;

  hipFuncSetAttribute((const void*)gnn_fused,
                      hipFuncAttributeMaxDynamicSharedMemorySize, LDS_BYTES);

  void* args[] = {&pos, &z, &batch, &emb, &W1, &b1, &W2, &b2, &W3, &b3,
                  &gsum, &gcnt, &Tpk, &outp};
  hipLaunchCooperativeKernel((void*)gnn_fused, dim3(NBLOCKS), dim3(NTHREADS),
                             args, LDS_BYTES, stream);
}